// Round 2
// baseline (193.108 us; speedup 1.0000x reference)
//
#include <hip/hip_runtime.h>

#define KNB 48

typedef float  floatx4 __attribute__((ext_vector_type(4)));
typedef __bf16 bf16x8  __attribute__((ext_vector_type(8)));
typedef unsigned short ushort8  __attribute__((ext_vector_type(8)));
typedef unsigned short ushort4v __attribute__((ext_vector_type(4)));

__device__ __forceinline__ float bf2f(unsigned short b) {
  union { unsigned int u; float f; } v; v.u = ((unsigned int)b) << 16; return v.f;
}
__device__ __forceinline__ unsigned short f2bf(float f) {
  union { float f; unsigned int u; } v; v.f = f;
  unsigned int r = v.u + 0x7fffu + ((v.u >> 16) & 1u);
  return (unsigned short)(r >> 16);
}
__device__ __forceinline__ float gelu_f(float x) {
  return 0.5f * x * (1.0f + erff(x * 0.70710678118654752440f));
}

// ---------------------------------------------------------------------------
// k0: transpose fp32 weights into bf16 [n][k] tables (MFMA B-frag friendly)
// blocks: [0,64) mW1(512x128)->MT1[128][512]; [64,80) mW2->WT2; [80,96) mW3->WT3;
//         [96,160) fW1(128x512)->FWT1[512][128]; [160,224) fW2(512x128)->FWT2[128][512]
// ---------------------------------------------------------------------------
__global__ __launch_bounds__(256) void k0_transpose(
    const float* mW1, const float* mW2, const float* mW3,
    const float* fW1, const float* fW2,
    unsigned short* MT1, unsigned short* WT2, unsigned short* WT3,
    unsigned short* FWT1, unsigned short* FWT2) {
  __shared__ unsigned short tile[32][33];
  int b = blockIdx.x;
  const float* src; unsigned short* dst; int Kd, Nd, t;
  if (b < 64)       { src = mW1; dst = MT1;  Kd = 512; Nd = 128; t = b; }
  else if (b < 80)  { src = mW2; dst = WT2;  Kd = 128; Nd = 128; t = b - 64; }
  else if (b < 96)  { src = mW3; dst = WT3;  Kd = 128; Nd = 128; t = b - 80; }
  else if (b < 160) { src = fW1; dst = FWT1; Kd = 128; Nd = 512; t = b - 96; }
  else              { src = fW2; dst = FWT2; Kd = 512; Nd = 128; t = b - 160; }
  int tN = Nd >> 5;
  int tk = t / tN, tn = t % tN;
  int tx = threadIdx.x & 31, ty = threadIdx.x >> 5;  // 32x8
  for (int r = 0; r < 4; ++r) {
    int row = ty + r * 8;
    tile[row][tx] = f2bf(src[(size_t)(tk * 32 + row) * Nd + tn * 32 + tx]);
  }
  __syncthreads();
  for (int r = 0; r < 4; ++r) {
    int row = ty + r * 8;
    dst[(size_t)(tn * 32 + row) * Kd + tk * 32 + tx] = tile[tx][row];
  }
}

// ---------------------------------------------------------------------------
// k1: node precompute tables:
//   Apr[i] = node_h[i] @ mW1[0:128]   + mb1          (fp32)
//   BS[j][0:128]   = node_h[j] @ mW1[128:256]        (bf16)
//   BS[j][128:256] = seq_emb[j] @ mW1[384:512]       (bf16)
// 256 blocks x 32 rows; 24 (kind,ntile) jobs over 4 waves.
// ---------------------------------------------------------------------------
__global__ __launch_bounds__(256) void k1_nodepre(
    const float* node_h, const float* seq_emb,
    const unsigned short* MT1, const float* mb1,
    float* Apr, unsigned short* BS) {
  __shared__ __align__(16) unsigned short sX[2][32 * 128];
  int r0 = blockIdx.x * 32;
  int tid = threadIdx.x, lane = tid & 63, w = tid >> 6;
  int l15 = lane & 15, l16 = lane >> 4;

  for (int mset = 0; mset < 2; ++mset) {
    const float* src = mset ? (seq_emb + (size_t)r0 * 128) : (node_h + (size_t)r0 * 128);
    for (int k = 0; k < 4; ++k) {
      int f = tid + 256 * k;                      // float4 chunk id [0,1024)
      floatx4 v = ((const floatx4*)src)[f];
      int row = f >> 5, hc = f & 31, c = hc >> 1, half = hc & 1;
      ushort4v o;
      o[0] = f2bf(v[0]); o[1] = f2bf(v[1]); o[2] = f2bf(v[2]); o[3] = f2bf(v[3]);
      *(ushort4v*)((char*)&sX[mset][0] + row * 256 + ((c ^ (row & 7)) << 4) + half * 8) = o;
    }
  }
  __syncthreads();

  for (int q = 0; q < 6; ++q) {
    int job = w + 4 * q;
    int kind = job >> 3;                 // 0:Apr 1:B 2:S
    int nt = job & 7;
    int colOff = (kind == 0) ? 0 : (kind == 1) ? 128 : 384;
    const unsigned short* X = sX[kind == 2 ? 1 : 0];
    bf16x8 wf[4];
    for (int kk = 0; kk < 4; ++kk)
      wf[kk] = *(const bf16x8*)(MT1 + (size_t)(nt * 16 + l15) * 512 + colOff + kk * 32 + l16 * 8);
    for (int mt = 0; mt < 2; ++mt) {
      floatx4 acc = {0.f, 0.f, 0.f, 0.f};
      for (int kk = 0; kk < 4; ++kk) {
        int row = mt * 16 + l15;
        int off = (kk * 64 + l16 * 16) ^ ((row & 7) << 4);
        bf16x8 a = *(const bf16x8*)((const char*)X + row * 256 + off);
        acc = __builtin_amdgcn_mfma_f32_16x16x32_bf16(a, wf[kk], acc, 0, 0, 0);
      }
      int col = nt * 16 + l15;
      for (int r = 0; r < 4; ++r) {
        int row = r0 + mt * 16 + l16 * 4 + r;
        if (kind == 0)      Apr[(size_t)row * 128 + col] = acc[r] + mb1[col];
        else if (kind == 1) BS[(size_t)row * 256 + col] = f2bf(acc[r]);
        else                BS[(size_t)row * 256 + 128 + col] = f2bf(acc[r]);
      }
    }
  }
}

// ---------------------------------------------------------------------------
// k2: main edge kernel. 1 block = 2 nodes = 96 edges. 4 waves.
//   gvec = Apr[i] + B[j] + m*S[j]                      -> sT (bf16, swizzled)
//   layer1: sE @ W1e + gvec -> gelu                    -> sT (in place)
//   layer2: sT @ W2 + mb2 -> gelu                      -> sE (overwrite)
//   layer3: sE @ W3, row-sum per node (+48*mb3)        -> agg (fp32)
// ---------------------------------------------------------------------------
__global__ __launch_bounds__(256) void k2_edge(
    const float* edge_h, const int* edge_idx, const float* ar_mask,
    const unsigned short* MT1, const unsigned short* WT2, const unsigned short* WT3,
    const float* mb2, const float* mb3,
    const float* Apr, const unsigned short* BS,
    float* agg) {
  __shared__ __align__(16) unsigned short sE[96 * 128];
  __shared__ __align__(16) unsigned short sT[96 * 128];
  __shared__ int   sJ[96];
  __shared__ float sM[96];
  int i0 = blockIdx.x * 2;
  int tid = threadIdx.x, lane = tid & 63, w = tid >> 6;
  int l15 = lane & 15, l16 = lane >> 4;

  if (tid < 96) {
    sJ[tid] = edge_idx[(size_t)i0 * KNB + tid];
    sM[tid] = ar_mask[(size_t)i0 * KNB + tid];
  }
  // stage edge_h tile (fp32 -> bf16, swizzled write)
  const float* eb = edge_h + (size_t)i0 * KNB * 128;
  for (int k = 0; k < 12; ++k) {
    int f = tid + 256 * k;                        // float4 chunk id [0,3072)
    floatx4 v = ((const floatx4*)eb)[f];
    int row = f >> 5, hc = f & 31, c = hc >> 1, half = hc & 1;
    ushort4v o;
    o[0] = f2bf(v[0]); o[1] = f2bf(v[1]); o[2] = f2bf(v[2]); o[3] = f2bf(v[3]);
    *(ushort4v*)((char*)sE + row * 256 + ((c ^ (row & 7)) << 4) + half * 8) = o;
  }
  __syncthreads();

  // gvec -> sT (bf16, swizzled)
  for (int u = tid; u < 96 * 16; u += 256) {
    int e = u >> 4, c8 = u & 15;
    int j = sJ[e]; float m = sM[e];
    int i = i0 + (e >= 48 ? 1 : 0);
    const floatx4* ap = (const floatx4*)(Apr + (size_t)i * 128 + c8 * 8);
    floatx4 a0 = ap[0], a1 = ap[1];
    ushort8 vb = *(const ushort8*)(BS + (size_t)j * 256 + c8 * 8);
    ushort8 vs = *(const ushort8*)(BS + (size_t)j * 256 + 128 + c8 * 8);
    ushort8 res;
#pragma unroll
    for (int x = 0; x < 4; ++x)
      res[x] = f2bf(a0[x] + bf2f(vb[x]) + m * bf2f(vs[x]));
#pragma unroll
    for (int x = 0; x < 4; ++x)
      res[4 + x] = f2bf(a1[x] + bf2f(vb[4 + x]) + m * bf2f(vs[4 + x]));
    *(ushort8*)((char*)sT + e * 256 + ((c8 ^ (e & 7)) * 16)) = res;
  }
  __syncthreads();

  // ---- layer 1: sE x W1e + gvec -> gelu -> sT
  {
    bf16x8 wf[2][4];
    for (int n = 0; n < 2; ++n)
      for (int kk = 0; kk < 4; ++kk)
        wf[n][kk] = *(const bf16x8*)(MT1 + (size_t)((2 * w + n) * 16 + l15) * 512 + 256 + kk * 32 + l16 * 8);
    for (int mt = 0; mt < 6; ++mt) {
      floatx4 acc0 = {0.f,0.f,0.f,0.f}, acc1 = {0.f,0.f,0.f,0.f};
      for (int kk = 0; kk < 4; ++kk) {
        int row = mt * 16 + l15;
        int off = (kk * 64 + l16 * 16) ^ ((row & 7) << 4);
        bf16x8 a = *(const bf16x8*)((const char*)sE + row * 256 + off);
        acc0 = __builtin_amdgcn_mfma_f32_16x16x32_bf16(a, wf[0][kk], acc0, 0, 0, 0);
        acc1 = __builtin_amdgcn_mfma_f32_16x16x32_bf16(a, wf[1][kk], acc1, 0, 0, 0);
      }
      for (int n = 0; n < 2; ++n) {
        floatx4 acc = n ? acc1 : acc0;
        int col = (2 * w + n) * 16 + l15;
        for (int r = 0; r < 4; ++r) {
          int row = mt * 16 + l16 * 4 + r;
          char* p = (char*)sT + row * 256 + ((((col >> 3) ^ (row & 7)) << 4) | ((col & 7) << 1));
          float g = bf2f(*(unsigned short*)p);
          *(unsigned short*)p = f2bf(gelu_f(acc[r] + g));
        }
      }
    }
  }
  __syncthreads();

  // ---- layer 2: sT x W2 + mb2 -> gelu -> sE
  {
    bf16x8 wf[2][4];
    for (int n = 0; n < 2; ++n)
      for (int kk = 0; kk < 4; ++kk)
        wf[n][kk] = *(const bf16x8*)(WT2 + (size_t)((2 * w + n) * 16 + l15) * 128 + kk * 32 + l16 * 8);
    for (int mt = 0; mt < 6; ++mt) {
      floatx4 acc0 = {0.f,0.f,0.f,0.f}, acc1 = {0.f,0.f,0.f,0.f};
      for (int kk = 0; kk < 4; ++kk) {
        int row = mt * 16 + l15;
        int off = (kk * 64 + l16 * 16) ^ ((row & 7) << 4);
        bf16x8 a = *(const bf16x8*)((const char*)sT + row * 256 + off);
        acc0 = __builtin_amdgcn_mfma_f32_16x16x32_bf16(a, wf[0][kk], acc0, 0, 0, 0);
        acc1 = __builtin_amdgcn_mfma_f32_16x16x32_bf16(a, wf[1][kk], acc1, 0, 0, 0);
      }
      for (int n = 0; n < 2; ++n) {
        floatx4 acc = n ? acc1 : acc0;
        int col = (2 * w + n) * 16 + l15;
        float bb = mb2[col];
        for (int r = 0; r < 4; ++r) {
          int row = mt * 16 + l16 * 4 + r;
          char* p = (char*)sE + row * 256 + ((((col >> 3) ^ (row & 7)) << 4) | ((col & 7) << 1));
          *(unsigned short*)p = f2bf(gelu_f(acc[r] + bb));
        }
      }
    }
  }
  __syncthreads();

  // ---- layer 3: sE x W3, aggregate rows per node
  {
    bf16x8 wf[2][4];
    for (int n = 0; n < 2; ++n)
      for (int kk = 0; kk < 4; ++kk)
        wf[n][kk] = *(const bf16x8*)(WT3 + (size_t)((2 * w + n) * 16 + l15) * 128 + kk * 32 + l16 * 8);
    for (int half = 0; half < 2; ++half) {
      float agga[2][4] = {{0.f,0.f,0.f,0.f},{0.f,0.f,0.f,0.f}};
      for (int mt3 = 0; mt3 < 3; ++mt3) {
        int mt = half * 3 + mt3;
        floatx4 acc0 = {0.f,0.f,0.f,0.f}, acc1 = {0.f,0.f,0.f,0.f};
        for (int kk = 0; kk < 4; ++kk) {
          int row = mt * 16 + l15;
          int off = (kk * 64 + l16 * 16) ^ ((row & 7) << 4);
          bf16x8 a = *(const bf16x8*)((const char*)sE + row * 256 + off);
          acc0 = __builtin_amdgcn_mfma_f32_16x16x32_bf16(a, wf[0][kk], acc0, 0, 0, 0);
          acc1 = __builtin_amdgcn_mfma_f32_16x16x32_bf16(a, wf[1][kk], acc1, 0, 0, 0);
        }
#pragma unroll
        for (int r = 0; r < 4; ++r) { agga[0][r] += acc0[r]; agga[1][r] += acc1[r]; }
      }
      for (int n = 0; n < 2; ++n) {
        float s = agga[n][0] + agga[n][1] + agga[n][2] + agga[n][3];
        s += __shfl_xor(s, 16);
        s += __shfl_xor(s, 32);
        if (lane < 16) {
          int col = (2 * w + n) * 16 + lane;
          agg[(size_t)(i0 + half) * 128 + col] = s + 48.0f * mb3[col];
        }
      }
    }
  }
}

// ---------------------------------------------------------------------------
// k3: node FF: h=LN(node_h+agg); ff=gelu(h@fW1+fb1)@fW2+fb2; out=LN(h+ff)
// 256 blocks x 32 rows, 4 waves.
// ---------------------------------------------------------------------------
__global__ __launch_bounds__(256) void k3_ff(
    const float* node_h, const float* agg,
    const unsigned short* FWT1, const unsigned short* FWT2,
    const float* fb1, const float* fb2,
    const float* g1, const float* b1,
    const float* g2, const float* b2,
    float* out) {
  __shared__ __align__(16) unsigned short sH[32 * 128];
  __shared__ __align__(16) unsigned short sT3[32 * 512];
  __shared__ float sP[32 * 128];
  int r0 = blockIdx.x * 32;
  int tid = threadIdx.x, lane = tid & 63, w = tid >> 6;
  int l15 = lane & 15, l16 = lane >> 4;

  // load + LN1
  {
    int row = tid >> 3;
    int c0 = (tid & 7) * 16;
    const floatx4* nh4 = (const floatx4*)(node_h + (size_t)(r0 + row) * 128 + c0);
    const floatx4* ag4 = (const floatx4*)(agg + (size_t)(r0 + row) * 128 + c0);
    float x[16]; float sum = 0.f, sum2 = 0.f;
#pragma unroll
    for (int q4 = 0; q4 < 4; ++q4) {
      floatx4 a = nh4[q4], g = ag4[q4];
#pragma unroll
      for (int j = 0; j < 4; ++j) {
        float xv = a[j] + g[j];
        x[q4 * 4 + j] = xv; sum += xv; sum2 += xv * xv;
      }
    }
    sum  += __shfl_xor(sum, 1);  sum  += __shfl_xor(sum, 2);  sum  += __shfl_xor(sum, 4);
    sum2 += __shfl_xor(sum2, 1); sum2 += __shfl_xor(sum2, 2); sum2 += __shfl_xor(sum2, 4);
    float mu = sum * (1.f / 128.f);
    float var = sum2 * (1.f / 128.f) - mu * mu;
    float rstd = rsqrtf(var + 1e-5f);
#pragma unroll
    for (int q = 0; q < 16; ++q) {
      int col = c0 + q;
      float h = (x[q] - mu) * rstd * g1[col] + b1[col];
      sP[row * 128 + col] = h;
      char* p = (char*)sH + row * 256 + ((((col >> 3) ^ (row & 7)) << 4) | ((col & 7) << 1));
      *(unsigned short*)p = f2bf(h);
    }
  }
  __syncthreads();

  // GEMM1: sH @ FWT1 -> gelu -> sT3   [32,128]x[128,512]
  for (int nq = 0; nq < 8; ++nq) {
    int nt = w * 8 + nq;
    bf16x8 wf[4];
    for (int kk = 0; kk < 4; ++kk)
      wf[kk] = *(const bf16x8*)(FWT1 + (size_t)(nt * 16 + l15) * 128 + kk * 32 + l16 * 8);
    for (int mt = 0; mt < 2; ++mt) {
      floatx4 acc = {0.f,0.f,0.f,0.f};
      for (int kk = 0; kk < 4; ++kk) {
        int row = mt * 16 + l15;
        int off = (kk * 64 + l16 * 16) ^ ((row & 7) << 4);
        bf16x8 a = *(const bf16x8*)((const char*)sH + row * 256 + off);
        acc = __builtin_amdgcn_mfma_f32_16x16x32_bf16(a, wf[kk], acc, 0, 0, 0);
      }
      int col = nt * 16 + l15;
      float bb = fb1[col];
      for (int r = 0; r < 4; ++r) {
        int row = mt * 16 + l16 * 4 + r;
        char* p = (char*)sT3 + row * 1024 + ((((col >> 3) ^ (row & 7)) << 4) | ((col & 7) << 1));
        *(unsigned short*)p = f2bf(gelu_f(acc[r] + bb));
      }
    }
  }
  __syncthreads();

  // GEMM2: sT3 @ FWT2 + fb2 + h -> sP   [32,512]x[512,128]
  for (int n = 0; n < 2; ++n) {
    int nt = 2 * w + n;
    for (int mt = 0; mt < 2; ++mt) {
      floatx4 acc = {0.f,0.f,0.f,0.f};
      for (int kk = 0; kk < 16; ++kk) {
        int row = mt * 16 + l15;
        int off = (kk * 64 + l16 * 16) ^ ((row & 7) << 4);
        bf16x8 a = *(const bf16x8*)((const char*)sT3 + row * 1024 + off);
        bf16x8 b = *(const bf16x8*)(FWT2 + (size_t)(nt * 16 + l15) * 512 + kk * 32 + l16 * 8);
        acc = __builtin_amdgcn_mfma_f32_16x16x32_bf16(a, b, acc, 0, 0, 0);
      }
      int col = nt * 16 + l15;
      float bb = fb2[col];
      for (int r = 0; r < 4; ++r) {
        int row = mt * 16 + l16 * 4 + r;
        sP[row * 128 + col] += acc[r] + bb;
      }
    }
  }
  __syncthreads();

  // LN2 + store (fp32)
  {
    int row = tid >> 3;
    int c0 = (tid & 7) * 16;
    float x[16]; float sum = 0.f, sum2 = 0.f;
#pragma unroll
    for (int q = 0; q < 16; ++q) {
      float xv = sP[row * 128 + c0 + q];
      x[q] = xv; sum += xv; sum2 += xv * xv;
    }
    sum  += __shfl_xor(sum, 1);  sum  += __shfl_xor(sum, 2);  sum  += __shfl_xor(sum, 4);
    sum2 += __shfl_xor(sum2, 1); sum2 += __shfl_xor(sum2, 2); sum2 += __shfl_xor(sum2, 4);
    float mu = sum * (1.f / 128.f);
    float var = sum2 * (1.f / 128.f) - mu * mu;
    float rstd = rsqrtf(var + 1e-5f);
#pragma unroll
    for (int q = 0; q < 16; ++q) {
      int col = c0 + q;
      out[(size_t)(r0 + row) * 128 + col] = (x[q] - mu) * rstd * g2[col] + b2[col];
    }
  }
}

// ---------------------------------------------------------------------------
extern "C" void kernel_launch(void* const* d_in, const int* in_sizes, int n_in,
                              void* d_out, int out_size, void* d_ws, size_t ws_size,
                              hipStream_t stream) {
  const float* node_h  = (const float*)d_in[0];
  const float* edge_h  = (const float*)d_in[1];
  const int*   edge_idx= (const int*)d_in[2];
  const float* seq_emb = (const float*)d_in[3];
  const float* ar_mask = (const float*)d_in[4];
  const float* mW1 = (const float*)d_in[5];
  const float* mb1 = (const float*)d_in[6];
  const float* mW2 = (const float*)d_in[7];
  const float* mb2 = (const float*)d_in[8];
  const float* mW3 = (const float*)d_in[9];
  const float* mb3 = (const float*)d_in[10];
  const float* fW1 = (const float*)d_in[11];
  const float* fb1 = (const float*)d_in[12];
  const float* fW2 = (const float*)d_in[13];
  const float* fb2 = (const float*)d_in[14];
  const float* g1  = (const float*)d_in[15];
  const float* b1  = (const float*)d_in[16];
  const float* g2  = (const float*)d_in[17];
  const float* b2  = (const float*)d_in[18];

  char* ws = (char*)d_ws;
  unsigned short* MT1  = (unsigned short*)(ws + 0);        // [128][512] bf16
  unsigned short* WT2  = (unsigned short*)(ws + 131072);   // [128][128] bf16
  unsigned short* WT3  = (unsigned short*)(ws + 163840);   // [128][128] bf16
  unsigned short* FWT1 = (unsigned short*)(ws + 196608);   // [512][128] bf16
  unsigned short* FWT2 = (unsigned short*)(ws + 327680);   // [128][512] bf16
  float*          Apr  = (float*)(ws + 458752);            // [8192][128] f32
  unsigned short* BS   = (unsigned short*)(ws + 4653056);  // [8192][256] bf16
  float*          agg  = (float*)(ws + 8847360);           // [8192][128] f32

  hipLaunchKernelGGL(k0_transpose, dim3(224), dim3(256), 0, stream,
                     mW1, mW2, mW3, fW1, fW2, MT1, WT2, WT3, FWT1, FWT2);
  hipLaunchKernelGGL(k1_nodepre, dim3(256), dim3(256), 0, stream,
                     node_h, seq_emb, MT1, mb1, Apr, BS);
  hipLaunchKernelGGL(k2_edge, dim3(4096), dim3(256), 0, stream,
                     edge_h, edge_idx, ar_mask, MT1, WT2, WT3, mb2, mb3,
                     Apr, BS, agg);
  hipLaunchKernelGGL(k3_ff, dim3(256), dim3(256), 0, stream,
                     node_h, agg, FWT1, FWT2, fb1, fb2, g1, b1, g2, b2,
                     (float*)d_out);
}

// Round 3
// 144.053 us; speedup vs baseline: 1.3405x; 1.3405x over previous
//
#include <hip/hip_runtime.h>

#define KNB 48

typedef float  floatx4 __attribute__((ext_vector_type(4)));
typedef __bf16 bf16x8  __attribute__((ext_vector_type(8)));
typedef unsigned short ushort8  __attribute__((ext_vector_type(8)));
typedef unsigned short ushort4v __attribute__((ext_vector_type(4)));

__device__ __forceinline__ float bf2f(unsigned short b) {
  union { unsigned int u; float f; } v; v.u = ((unsigned int)b) << 16; return v.f;
}
__device__ __forceinline__ unsigned short f2bf(float f) {
  __bf16 h = (__bf16)f;
  union { __bf16 h; unsigned short u; } v; v.h = h; return v.u;
}
// GELU via sigmoid-form tanh approximation:
//   gelu(x) ~= x * sigmoid(2*0.7978845608*(x + 0.044715 x^3))
// max |err| vs exact erf-GELU ~3e-4, far below bf16 rounding noise here.
__device__ __forceinline__ float gelu_f(float x) {
  float u = x * (0.7978845608f + 0.0356774081f * x * x);  // 0.79788*x + 0.79788*0.044715*x^3
  float t = __builtin_amdgcn_exp2f(u * -2.8853900818f);   // exp(-2u) = 2^(-2u*log2 e)
  return x * __builtin_amdgcn_rcpf(1.0f + t);
}

// ---------------------------------------------------------------------------
// k0: transpose fp32 weights into bf16 [n][k] tables (MFMA B-frag friendly)
// blocks: [0,64) mW1(512x128)->MT1[128][512]; [64,80) mW2->WT2; [80,96) mW3->WT3;
//         [96,160) fW1(128x512)->FWT1[512][128]; [160,224) fW2(512x128)->FWT2[128][512]
// ---------------------------------------------------------------------------
__global__ __launch_bounds__(256) void k0_transpose(
    const float* mW1, const float* mW2, const float* mW3,
    const float* fW1, const float* fW2,
    unsigned short* MT1, unsigned short* WT2, unsigned short* WT3,
    unsigned short* FWT1, unsigned short* FWT2) {
  __shared__ unsigned short tile[32][33];
  int b = blockIdx.x;
  const float* src; unsigned short* dst; int Kd, Nd, t;
  if (b < 64)       { src = mW1; dst = MT1;  Kd = 512; Nd = 128; t = b; }
  else if (b < 80)  { src = mW2; dst = WT2;  Kd = 128; Nd = 128; t = b - 64; }
  else if (b < 96)  { src = mW3; dst = WT3;  Kd = 128; Nd = 128; t = b - 80; }
  else if (b < 160) { src = fW1; dst = FWT1; Kd = 128; Nd = 512; t = b - 96; }
  else              { src = fW2; dst = FWT2; Kd = 512; Nd = 128; t = b - 160; }
  int tN = Nd >> 5;
  int tk = t / tN, tn = t % tN;
  int tx = threadIdx.x & 31, ty = threadIdx.x >> 5;  // 32x8
  for (int r = 0; r < 4; ++r) {
    int row = ty + r * 8;
    tile[row][tx] = f2bf(src[(size_t)(tk * 32 + row) * Nd + tn * 32 + tx]);
  }
  __syncthreads();
  for (int r = 0; r < 4; ++r) {
    int row = ty + r * 8;
    dst[(size_t)(tn * 32 + row) * Kd + tk * 32 + tx] = tile[tx][row];
  }
}

// ---------------------------------------------------------------------------
// k1: node precompute tables:
//   Apr[i] = node_h[i] @ mW1[0:128]   + mb1          (fp32)
//   BS[j][0:128]   = node_h[j] @ mW1[128:256]        (bf16)
//   BS[j][128:256] = seq_emb[j] @ mW1[384:512]       (bf16)
// ---------------------------------------------------------------------------
__global__ __launch_bounds__(256) void k1_nodepre(
    const float* node_h, const float* seq_emb,
    const unsigned short* MT1, const float* mb1,
    float* Apr, unsigned short* BS) {
  __shared__ __align__(16) unsigned short sX[2][32 * 128];
  int r0 = blockIdx.x * 32;
  int tid = threadIdx.x, lane = tid & 63, w = tid >> 6;
  int l15 = lane & 15, l16 = lane >> 4;

  for (int mset = 0; mset < 2; ++mset) {
    const float* src = mset ? (seq_emb + (size_t)r0 * 128) : (node_h + (size_t)r0 * 128);
    for (int k = 0; k < 4; ++k) {
      int f = tid + 256 * k;                      // float4 chunk id [0,1024)
      floatx4 v = ((const floatx4*)src)[f];
      int row = f >> 5, hc = f & 31, c = hc >> 1, half = hc & 1;
      ushort4v o;
      o[0] = f2bf(v[0]); o[1] = f2bf(v[1]); o[2] = f2bf(v[2]); o[3] = f2bf(v[3]);
      *(ushort4v*)((char*)&sX[mset][0] + row * 256 + ((c ^ (row & 7)) << 4) + half * 8) = o;
    }
  }
  __syncthreads();

  for (int q = 0; q < 6; ++q) {
    int job = w + 4 * q;
    int kind = job >> 3;                 // 0:Apr 1:B 2:S
    int nt = job & 7;
    int colOff = (kind == 0) ? 0 : (kind == 1) ? 128 : 384;
    const unsigned short* X = sX[kind == 2 ? 1 : 0];
    bf16x8 wf[4];
    for (int kk = 0; kk < 4; ++kk)
      wf[kk] = *(const bf16x8*)(MT1 + (size_t)(nt * 16 + l15) * 512 + colOff + kk * 32 + l16 * 8);
    for (int mt = 0; mt < 2; ++mt) {
      floatx4 acc = {0.f, 0.f, 0.f, 0.f};
      for (int kk = 0; kk < 4; ++kk) {
        int row = mt * 16 + l15;
        int off = (kk * 64 + l16 * 16) ^ ((row & 7) << 4);
        bf16x8 a = *(const bf16x8*)((const char*)X + row * 256 + off);
        acc = __builtin_amdgcn_mfma_f32_16x16x32_bf16(a, wf[kk], acc, 0, 0, 0);
      }
      int col = nt * 16 + l15;
      for (int r = 0; r < 4; ++r) {
        int row = r0 + mt * 16 + l16 * 4 + r;
        if (kind == 0)      Apr[(size_t)row * 128 + col] = acc[r] + mb1[col];
        else if (kind == 1) BS[(size_t)row * 256 + col] = f2bf(acc[r]);
        else                BS[(size_t)row * 256 + 128 + col] = f2bf(acc[r]);
      }
    }
  }
}

// ---------------------------------------------------------------------------
// k2: main edge kernel. 1 block = 2 nodes = 96 edges. 4 waves.
// ---------------------------------------------------------------------------
__global__ __launch_bounds__(256) void k2_edge(
    const float* edge_h, const int* edge_idx, const float* ar_mask,
    const unsigned short* MT1, const unsigned short* WT2, const unsigned short* WT3,
    const float* mb2, const float* mb3,
    const float* Apr, const unsigned short* BS,
    float* agg) {
  __shared__ __align__(16) unsigned short sE[96 * 128];
  __shared__ __align__(16) unsigned short sT[96 * 128];
  __shared__ int   sJ[96];
  __shared__ float sM[96];
  int i0 = blockIdx.x * 2;
  int tid = threadIdx.x, lane = tid & 63, w = tid >> 6;
  int l15 = lane & 15, l16 = lane >> 4;
  int rb = (l16 & 1) * 4;                 // (row&7) = rb + r for row = mt*16 + l16*4 + r

  if (tid < 96) {
    sJ[tid] = edge_idx[(size_t)i0 * KNB + tid];
    sM[tid] = ar_mask[(size_t)i0 * KNB + tid];
  }
  // stage edge_h tile (fp32 -> bf16, swizzled write)
  const float* eb = edge_h + (size_t)i0 * KNB * 128;
  for (int k = 0; k < 12; ++k) {
    int f = tid + 256 * k;                        // float4 chunk id [0,3072)
    floatx4 v = ((const floatx4*)eb)[f];
    int row = f >> 5, hc = f & 31, c = hc >> 1, half = hc & 1;
    ushort4v o;
    o[0] = f2bf(v[0]); o[1] = f2bf(v[1]); o[2] = f2bf(v[2]); o[3] = f2bf(v[3]);
    *(ushort4v*)((char*)sE + row * 256 + ((c ^ (row & 7)) << 4) + half * 8) = o;
  }
  __syncthreads();

  // gvec = Apr[i] + B[j] + m*S[j]  -> sT (bf16, swizzled)
  for (int u = tid; u < 96 * 16; u += 256) {
    int e = u >> 4, c8 = u & 15;
    int j = sJ[e]; float m = sM[e];
    int i = i0 + (e >= 48 ? 1 : 0);
    const floatx4* ap = (const floatx4*)(Apr + (size_t)i * 128 + c8 * 8);
    floatx4 a0 = ap[0], a1 = ap[1];
    ushort8 vb = *(const ushort8*)(BS + (size_t)j * 256 + c8 * 8);
    ushort8 vs = *(const ushort8*)(BS + (size_t)j * 256 + 128 + c8 * 8);
    ushort8 res;
#pragma unroll
    for (int x = 0; x < 4; ++x)
      res[x] = f2bf(a0[x] + bf2f(vb[x]) + m * bf2f(vs[x]));
#pragma unroll
    for (int x = 0; x < 4; ++x)
      res[4 + x] = f2bf(a1[x] + bf2f(vb[4 + x]) + m * bf2f(vs[4 + x]));
    *(ushort8*)((char*)sT + e * 256 + ((c8 ^ (e & 7)) * 16)) = res;
  }
  __syncthreads();

  // ---- layer 1: sE x W1e + gvec -> gelu -> sT
  {
    bf16x8 wf[2][4];
    for (int n = 0; n < 2; ++n)
      for (int kk = 0; kk < 4; ++kk)
        wf[n][kk] = *(const bf16x8*)(MT1 + (size_t)((2 * w + n) * 16 + l15) * 512 + 256 + kk * 32 + l16 * 8);
    int cp0 = ((((2 * w) * 16 + l15) >> 3) << 4) | ((l15 & 7) << 1);   // col part, n=0
    int cp1 = ((((2 * w + 1) * 16 + l15) >> 3) << 4) | ((l15 & 7) << 1);
    for (int mt = 0; mt < 6; ++mt) {
      floatx4 acc0 = {0.f,0.f,0.f,0.f}, acc1 = {0.f,0.f,0.f,0.f};
      for (int kk = 0; kk < 4; ++kk) {
        int row = mt * 16 + l15;
        int off = (kk * 64 + l16 * 16) ^ ((row & 7) << 4);
        bf16x8 a = *(const bf16x8*)((const char*)sE + row * 256 + off);
        acc0 = __builtin_amdgcn_mfma_f32_16x16x32_bf16(a, wf[0][kk], acc0, 0, 0, 0);
        acc1 = __builtin_amdgcn_mfma_f32_16x16x32_bf16(a, wf[1][kk], acc1, 0, 0, 0);
      }
      char* base = (char*)sT + (mt * 16 + l16 * 4) * 256;
#pragma unroll
      for (int r = 0; r < 4; ++r) {
        int sw = (rb + r) << 4;
        char* p0 = base + r * 256 + (cp0 ^ sw);
        char* p1 = base + r * 256 + (cp1 ^ sw);
        float g0 = bf2f(*(unsigned short*)p0);
        float g1v = bf2f(*(unsigned short*)p1);
        *(unsigned short*)p0 = f2bf(gelu_f(acc0[r] + g0));
        *(unsigned short*)p1 = f2bf(gelu_f(acc1[r] + g1v));
      }
    }
  }
  __syncthreads();

  // ---- layer 2: sT x W2 + mb2 -> gelu -> sE
  {
    bf16x8 wf[2][4];
    for (int n = 0; n < 2; ++n)
      for (int kk = 0; kk < 4; ++kk)
        wf[n][kk] = *(const bf16x8*)(WT2 + (size_t)((2 * w + n) * 16 + l15) * 128 + kk * 32 + l16 * 8);
    int cp0 = ((((2 * w) * 16 + l15) >> 3) << 4) | ((l15 & 7) << 1);
    int cp1 = ((((2 * w + 1) * 16 + l15) >> 3) << 4) | ((l15 & 7) << 1);
    float bb0 = mb2[(2 * w) * 16 + l15];
    float bb1 = mb2[(2 * w + 1) * 16 + l15];
    for (int mt = 0; mt < 6; ++mt) {
      floatx4 acc0 = {0.f,0.f,0.f,0.f}, acc1 = {0.f,0.f,0.f,0.f};
      for (int kk = 0; kk < 4; ++kk) {
        int row = mt * 16 + l15;
        int off = (kk * 64 + l16 * 16) ^ ((row & 7) << 4);
        bf16x8 a = *(const bf16x8*)((const char*)sT + row * 256 + off);
        acc0 = __builtin_amdgcn_mfma_f32_16x16x32_bf16(a, wf[0][kk], acc0, 0, 0, 0);
        acc1 = __builtin_amdgcn_mfma_f32_16x16x32_bf16(a, wf[1][kk], acc1, 0, 0, 0);
      }
      char* base = (char*)sE + (mt * 16 + l16 * 4) * 256;
#pragma unroll
      for (int r = 0; r < 4; ++r) {
        int sw = (rb + r) << 4;
        *(unsigned short*)(base + r * 256 + (cp0 ^ sw)) = f2bf(gelu_f(acc0[r] + bb0));
        *(unsigned short*)(base + r * 256 + (cp1 ^ sw)) = f2bf(gelu_f(acc1[r] + bb1));
      }
    }
  }
  __syncthreads();

  // ---- layer 3: sE x W3, aggregate rows per node
  {
    bf16x8 wf[2][4];
    for (int n = 0; n < 2; ++n)
      for (int kk = 0; kk < 4; ++kk)
        wf[n][kk] = *(const bf16x8*)(WT3 + (size_t)((2 * w + n) * 16 + l15) * 128 + kk * 32 + l16 * 8);
    for (int half = 0; half < 2; ++half) {
      float agga[2][4] = {{0.f,0.f,0.f,0.f},{0.f,0.f,0.f,0.f}};
      for (int mt3 = 0; mt3 < 3; ++mt3) {
        int mt = half * 3 + mt3;
        floatx4 acc0 = {0.f,0.f,0.f,0.f}, acc1 = {0.f,0.f,0.f,0.f};
        for (int kk = 0; kk < 4; ++kk) {
          int row = mt * 16 + l15;
          int off = (kk * 64 + l16 * 16) ^ ((row & 7) << 4);
          bf16x8 a = *(const bf16x8*)((const char*)sE + row * 256 + off);
          acc0 = __builtin_amdgcn_mfma_f32_16x16x32_bf16(a, wf[0][kk], acc0, 0, 0, 0);
          acc1 = __builtin_amdgcn_mfma_f32_16x16x32_bf16(a, wf[1][kk], acc1, 0, 0, 0);
        }
#pragma unroll
        for (int r = 0; r < 4; ++r) { agga[0][r] += acc0[r]; agga[1][r] += acc1[r]; }
      }
      for (int n = 0; n < 2; ++n) {
        float s = agga[n][0] + agga[n][1] + agga[n][2] + agga[n][3];
        s += __shfl_xor(s, 16);
        s += __shfl_xor(s, 32);
        if (lane < 16) {
          int col = (2 * w + n) * 16 + lane;
          agg[(size_t)(i0 + half) * 128 + col] = s + 48.0f * mb3[col];
        }
      }
    }
  }
}

// ---------------------------------------------------------------------------
// k3: node FF: h=LN(node_h+agg); ff=gelu(h@fW1+fb1)@fW2+fb2; out=LN(h+ff)
// ---------------------------------------------------------------------------
__global__ __launch_bounds__(256) void k3_ff(
    const float* node_h, const float* agg,
    const unsigned short* FWT1, const unsigned short* FWT2,
    const float* fb1, const float* fb2,
    const float* g1, const float* b1,
    const float* g2, const float* b2,
    float* out) {
  __shared__ __align__(16) unsigned short sH[32 * 128];
  __shared__ __align__(16) unsigned short sT3[32 * 512];
  __shared__ float sP[32 * 128];
  int r0 = blockIdx.x * 32;
  int tid = threadIdx.x, lane = tid & 63, w = tid >> 6;
  int l15 = lane & 15, l16 = lane >> 4;

  // load + LN1
  {
    int row = tid >> 3;
    int c0 = (tid & 7) * 16;
    const floatx4* nh4 = (const floatx4*)(node_h + (size_t)(r0 + row) * 128 + c0);
    const floatx4* ag4 = (const floatx4*)(agg + (size_t)(r0 + row) * 128 + c0);
    float x[16]; float sum = 0.f, sum2 = 0.f;
#pragma unroll
    for (int q4 = 0; q4 < 4; ++q4) {
      floatx4 a = nh4[q4], g = ag4[q4];
#pragma unroll
      for (int j = 0; j < 4; ++j) {
        float xv = a[j] + g[j];
        x[q4 * 4 + j] = xv; sum += xv; sum2 += xv * xv;
      }
    }
    sum  += __shfl_xor(sum, 1);  sum  += __shfl_xor(sum, 2);  sum  += __shfl_xor(sum, 4);
    sum2 += __shfl_xor(sum2, 1); sum2 += __shfl_xor(sum2, 2); sum2 += __shfl_xor(sum2, 4);
    float mu = sum * (1.f / 128.f);
    float var = sum2 * (1.f / 128.f) - mu * mu;
    float rstd = rsqrtf(var + 1e-5f);
#pragma unroll
    for (int q = 0; q < 16; ++q) {
      int col = c0 + q;
      float h = (x[q] - mu) * rstd * g1[col] + b1[col];
      sP[row * 128 + col] = h;
      char* p = (char*)sH + row * 256 + ((((col >> 3) ^ (row & 7)) << 4) | ((col & 7) << 1));
      *(unsigned short*)p = f2bf(h);
    }
  }
  __syncthreads();

  // GEMM1: sH @ FWT1 -> gelu -> sT3   [32,128]x[128,512]
  for (int nq = 0; nq < 8; ++nq) {
    int nt = w * 8 + nq;
    bf16x8 wf[4];
    for (int kk = 0; kk < 4; ++kk)
      wf[kk] = *(const bf16x8*)(FWT1 + (size_t)(nt * 16 + l15) * 128 + kk * 32 + l16 * 8);
    for (int mt = 0; mt < 2; ++mt) {
      floatx4 acc = {0.f,0.f,0.f,0.f};
      for (int kk = 0; kk < 4; ++kk) {
        int row = mt * 16 + l15;
        int off = (kk * 64 + l16 * 16) ^ ((row & 7) << 4);
        bf16x8 a = *(const bf16x8*)((const char*)sH + row * 256 + off);
        acc = __builtin_amdgcn_mfma_f32_16x16x32_bf16(a, wf[kk], acc, 0, 0, 0);
      }
      int col = nt * 16 + l15;
      float bb = fb1[col];
      for (int r = 0; r < 4; ++r) {
        int row = mt * 16 + l16 * 4 + r;
        char* p = (char*)sT3 + row * 1024 + ((((col >> 3) ^ (row & 7)) << 4) | ((col & 7) << 1));
        *(unsigned short*)p = f2bf(gelu_f(acc[r] + bb));
      }
    }
  }
  __syncthreads();

  // GEMM2: sT3 @ FWT2 + fb2 + h -> sP   [32,512]x[512,128]
  for (int n = 0; n < 2; ++n) {
    int nt = 2 * w + n;
    for (int mt = 0; mt < 2; ++mt) {
      floatx4 acc = {0.f,0.f,0.f,0.f};
      for (int kk = 0; kk < 16; ++kk) {
        int row = mt * 16 + l15;
        int off = (kk * 64 + l16 * 16) ^ ((row & 7) << 4);
        bf16x8 a = *(const bf16x8*)((const char*)sT3 + row * 1024 + off);
        bf16x8 b = *(const bf16x8*)(FWT2 + (size_t)(nt * 16 + l15) * 512 + kk * 32 + l16 * 8);
        acc = __builtin_amdgcn_mfma_f32_16x16x32_bf16(a, b, acc, 0, 0, 0);
      }
      int col = nt * 16 + l15;
      float bb = fb2[col];
      for (int r = 0; r < 4; ++r) {
        int row = mt * 16 + l16 * 4 + r;
        sP[row * 128 + col] += acc[r] + bb;
      }
    }
  }
  __syncthreads();

  // LN2 + store (fp32)
  {
    int row = tid >> 3;
    int c0 = (tid & 7) * 16;
    float x[16]; float sum = 0.f, sum2 = 0.f;
#pragma unroll
    for (int q = 0; q < 16; ++q) {
      float xv = sP[row * 128 + c0 + q];
      x[q] = xv; sum += xv; sum2 += xv * xv;
    }
    sum  += __shfl_xor(sum, 1);  sum  += __shfl_xor(sum, 2);  sum  += __shfl_xor(sum, 4);
    sum2 += __shfl_xor(sum2, 1); sum2 += __shfl_xor(sum2, 2); sum2 += __shfl_xor(sum2, 4);
    float mu = sum * (1.f / 128.f);
    float var = sum2 * (1.f / 128.f) - mu * mu;
    float rstd = rsqrtf(var + 1e-5f);
#pragma unroll
    for (int q = 0; q < 16; ++q) {
      int col = c0 + q;
      out[(size_t)(r0 + row) * 128 + col] = (x[q] - mu) * rstd * g2[col] + b2[col];
    }
  }
}

// ---------------------------------------------------------------------------
extern "C" void kernel_launch(void* const* d_in, const int* in_sizes, int n_in,
                              void* d_out, int out_size, void* d_ws, size_t ws_size,
                              hipStream_t stream) {
  const float* node_h  = (const float*)d_in[0];
  const float* edge_h  = (const float*)d_in[1];
  const int*   edge_idx= (const int*)d_in[2];
  const float* seq_emb = (const float*)d_in[3];
  const float* ar_mask = (const float*)d_in[4];
  const float* mW1 = (const float*)d_in[5];
  const float* mb1 = (const float*)d_in[6];
  const float* mW2 = (const float*)d_in[7];
  const float* mb2 = (const float*)d_in[8];
  const float* mW3 = (const float*)d_in[9];
  const float* mb3 = (const float*)d_in[10];
  const float* fW1 = (const float*)d_in[11];
  const float* fb1 = (const float*)d_in[12];
  const float* fW2 = (const float*)d_in[13];
  const float* fb2 = (const float*)d_in[14];
  const float* g1  = (const float*)d_in[15];
  const float* b1  = (const float*)d_in[16];
  const float* g2  = (const float*)d_in[17];
  const float* b2  = (const float*)d_in[18];

  char* ws = (char*)d_ws;
  unsigned short* MT1  = (unsigned short*)(ws + 0);        // [128][512] bf16
  unsigned short* WT2  = (unsigned short*)(ws + 131072);   // [128][128] bf16
  unsigned short* WT3  = (unsigned short*)(ws + 163840);   // [128][128] bf16
  unsigned short* FWT1 = (unsigned short*)(ws + 196608);   // [512][128] bf16
  unsigned short* FWT2 = (unsigned short*)(ws + 327680);   // [128][512] bf16
  float*          Apr  = (float*)(ws + 458752);            // [8192][128] f32
  unsigned short* BS   = (unsigned short*)(ws + 4653056);  // [8192][256] bf16
  float*          agg  = (float*)(ws + 8847360);           // [8192][128] f32

  hipLaunchKernelGGL(k0_transpose, dim3(224), dim3(256), 0, stream,
                     mW1, mW2, mW3, fW1, fW2, MT1, WT2, WT3, FWT1, FWT2);
  hipLaunchKernelGGL(k1_nodepre, dim3(256), dim3(256), 0, stream,
                     node_h, seq_emb, MT1, mb1, Apr, BS);
  hipLaunchKernelGGL(k2_edge, dim3(4096), dim3(256), 0, stream,
                     edge_h, edge_idx, ar_mask, MT1, WT2, WT3, mb2, mb3,
                     Apr, BS, agg);
  hipLaunchKernelGGL(k3_ff, dim3(256), dim3(256), 0, stream,
                     node_h, agg, FWT1, FWT2, fb1, fb2, g1, b1, g2, b2,
                     (float*)d_out);
}

// Round 4
// 139.537 us; speedup vs baseline: 1.3839x; 1.0324x over previous
//
#include <hip/hip_runtime.h>

#define KNB 48

typedef float  floatx4 __attribute__((ext_vector_type(4)));
typedef __bf16 bf16x8  __attribute__((ext_vector_type(8)));
typedef unsigned short ushort8  __attribute__((ext_vector_type(8)));
typedef unsigned short ushort4v __attribute__((ext_vector_type(4)));

__device__ __forceinline__ float bf2f(unsigned short b) {
  union { unsigned int u; float f; } v; v.u = ((unsigned int)b) << 16; return v.f;
}
__device__ __forceinline__ unsigned short f2bf(float f) {
  __bf16 h = (__bf16)f;
  union { __bf16 h; unsigned short u; } v; v.h = h; return v.u;
}
// GELU via sigmoid-form tanh approximation (max |err| ~3e-4 vs exact).
__device__ __forceinline__ float gelu_f(float x) {
  float u = x * (0.7978845608f + 0.0356774081f * x * x);
  float t = __builtin_amdgcn_exp2f(u * -2.8853900818f);
  return x * __builtin_amdgcn_rcpf(1.0f + t);
}

// ---------------------------------------------------------------------------
// k0: transpose fp32 weights into bf16 [n][k] tables
// ---------------------------------------------------------------------------
__global__ __launch_bounds__(256) void k0_transpose(
    const float* mW1, const float* mW2, const float* mW3,
    const float* fW1, const float* fW2,
    unsigned short* MT1, unsigned short* WT2, unsigned short* WT3,
    unsigned short* FWT1, unsigned short* FWT2) {
  __shared__ unsigned short tile[32][33];
  int b = blockIdx.x;
  const float* src; unsigned short* dst; int Kd, Nd, t;
  if (b < 64)       { src = mW1; dst = MT1;  Kd = 512; Nd = 128; t = b; }
  else if (b < 80)  { src = mW2; dst = WT2;  Kd = 128; Nd = 128; t = b - 64; }
  else if (b < 96)  { src = mW3; dst = WT3;  Kd = 128; Nd = 128; t = b - 80; }
  else if (b < 160) { src = fW1; dst = FWT1; Kd = 128; Nd = 512; t = b - 96; }
  else              { src = fW2; dst = FWT2; Kd = 512; Nd = 128; t = b - 160; }
  int tN = Nd >> 5;
  int tk = t / tN, tn = t % tN;
  int tx = threadIdx.x & 31, ty = threadIdx.x >> 5;  // 32x8
  for (int r = 0; r < 4; ++r) {
    int row = ty + r * 8;
    tile[row][tx] = f2bf(src[(size_t)(tk * 32 + row) * Nd + tn * 32 + tx]);
  }
  __syncthreads();
  for (int r = 0; r < 4; ++r) {
    int row = ty + r * 8;
    dst[(size_t)(tn * 32 + row) * Kd + tk * 32 + tx] = tile[tx][row];
  }
}

// ---------------------------------------------------------------------------
// k1: node precompute tables:
//   Apr[i] = node_h[i] @ mW1[0:128]   + mb1          (fp32)
//   BS[j][0:128]   = node_h[j] @ mW1[128:256]        (bf16)
//   BS[j][128:256] = seq_emb[j] @ mW1[384:512]       (bf16)
// ---------------------------------------------------------------------------
__global__ __launch_bounds__(256) void k1_nodepre(
    const float* node_h, const float* seq_emb,
    const unsigned short* MT1, const float* mb1,
    float* Apr, unsigned short* BS) {
  __shared__ __align__(16) unsigned short sX[2][32 * 128];
  int r0 = blockIdx.x * 32;
  int tid = threadIdx.x, lane = tid & 63, w = tid >> 6;
  int l15 = lane & 15, l16 = lane >> 4;

  for (int mset = 0; mset < 2; ++mset) {
    const float* src = mset ? (seq_emb + (size_t)r0 * 128) : (node_h + (size_t)r0 * 128);
    for (int k = 0; k < 4; ++k) {
      int f = tid + 256 * k;
      floatx4 v = ((const floatx4*)src)[f];
      int row = f >> 5, hc = f & 31, c = hc >> 1, half = hc & 1;
      ushort4v o;
      o[0] = f2bf(v[0]); o[1] = f2bf(v[1]); o[2] = f2bf(v[2]); o[3] = f2bf(v[3]);
      *(ushort4v*)((char*)&sX[mset][0] + row * 256 + ((c ^ (row & 7)) << 4) + half * 8) = o;
    }
  }
  __syncthreads();

  for (int q = 0; q < 6; ++q) {
    int job = w + 4 * q;
    int kind = job >> 3;                 // 0:Apr 1:B 2:S
    int nt = job & 7;
    int colOff = (kind == 0) ? 0 : (kind == 1) ? 128 : 384;
    const unsigned short* X = sX[kind == 2 ? 1 : 0];
    bf16x8 wf[4];
    for (int kk = 0; kk < 4; ++kk)
      wf[kk] = *(const bf16x8*)(MT1 + (size_t)(nt * 16 + l15) * 512 + colOff + kk * 32 + l16 * 8);
    for (int mt = 0; mt < 2; ++mt) {
      floatx4 acc = {0.f, 0.f, 0.f, 0.f};
      for (int kk = 0; kk < 4; ++kk) {
        int row = mt * 16 + l15;
        int off = (kk * 64 + l16 * 16) ^ ((row & 7) << 4);
        bf16x8 a = *(const bf16x8*)((const char*)X + row * 256 + off);
        acc = __builtin_amdgcn_mfma_f32_16x16x32_bf16(a, wf[kk], acc, 0, 0, 0);
      }
      int col = nt * 16 + l15;
      for (int r = 0; r < 4; ++r) {
        int row = r0 + mt * 16 + l16 * 4 + r;
        if (kind == 0)      Apr[(size_t)row * 128 + col] = acc[r] + mb1[col];
        else if (kind == 1) BS[(size_t)row * 256 + col] = f2bf(acc[r]);
        else                BS[(size_t)row * 256 + 128 + col] = f2bf(acc[r]);
      }
    }
  }
}

// ---------------------------------------------------------------------------
// k2: main edge kernel. 1 block = 2 nodes = 96 edges. 8 waves (512 thr),
// each wave owns one 16-col n-tile. 3 barriers total.
// ---------------------------------------------------------------------------
__global__ __launch_bounds__(512) void k2_edge(
    const float* edge_h, const int* edge_idx, const float* ar_mask,
    const unsigned short* MT1, const unsigned short* WT2, const unsigned short* WT3,
    const float* mb2, const float* mb3,
    const float* Apr, const unsigned short* BS,
    float* agg) {
  __shared__ __align__(16) unsigned short sE[96 * 128];
  __shared__ __align__(16) unsigned short sT[96 * 128];
  int i0 = blockIdx.x * 2;
  int tid = threadIdx.x, lane = tid & 63, w = tid >> 6;   // w in [0,8)
  int l15 = lane & 15, l16 = lane >> 4;
  int rb = (l16 & 1) * 4;                 // (row&7) = rb + r for row = mt*16 + l16*4 + r
  int colw = w * 16 + l15;                // this wave's output column
  int cp = ((colw >> 3) << 4) | ((l15 & 7) << 1);   // swizzle col-part

  // ---- phase 0: stage edge_h tile (fp32 -> bf16, swizzled) + gvec -> sT
  const float* eb = edge_h + (size_t)i0 * KNB * 128;
#pragma unroll
  for (int k = 0; k < 6; ++k) {
    int f = tid + 512 * k;                        // float4 chunk id [0,3072)
    floatx4 v = ((const floatx4*)eb)[f];
    int row = f >> 5, hc = f & 31, c = hc >> 1, half = hc & 1;
    ushort4v o;
    o[0] = f2bf(v[0]); o[1] = f2bf(v[1]); o[2] = f2bf(v[2]); o[3] = f2bf(v[3]);
    *(ushort4v*)((char*)sE + row * 256 + ((c ^ (row & 7)) << 4) + half * 8) = o;
  }
  // gvec = Apr[i] + B[j] + m*S[j]  -> sT (bf16, swizzled); idx/mask read direct
#pragma unroll
  for (int k = 0; k < 3; ++k) {
    int u = tid + 512 * k;                        // [0,1536)
    int e = u >> 4, c8 = u & 15;
    int j = edge_idx[(size_t)i0 * KNB + e];
    float m = ar_mask[(size_t)i0 * KNB + e];
    int i = i0 + (e >= 48 ? 1 : 0);
    const floatx4* ap = (const floatx4*)(Apr + (size_t)i * 128 + c8 * 8);
    floatx4 a0 = ap[0], a1 = ap[1];
    ushort8 vb = *(const ushort8*)(BS + (size_t)j * 256 + c8 * 8);
    ushort8 vs = *(const ushort8*)(BS + (size_t)j * 256 + 128 + c8 * 8);
    ushort8 res;
#pragma unroll
    for (int x = 0; x < 4; ++x)
      res[x] = f2bf(a0[x] + bf2f(vb[x]) + m * bf2f(vs[x]));
#pragma unroll
    for (int x = 0; x < 4; ++x)
      res[4 + x] = f2bf(a1[x] + bf2f(vb[4 + x]) + m * bf2f(vs[4 + x]));
    *(ushort8*)((char*)sT + e * 256 + ((c8 ^ (e & 7)) * 16)) = res;
  }
  __syncthreads();

  // ---- layer 1: sE x W1e + gvec -> gelu -> sT  (wave w: cols w*16..+15)
  {
    bf16x8 wf[4];
#pragma unroll
    for (int kk = 0; kk < 4; ++kk)
      wf[kk] = *(const bf16x8*)(MT1 + (size_t)colw * 512 + 256 + kk * 32 + l16 * 8);
    for (int mt = 0; mt < 6; ++mt) {
      floatx4 acc = {0.f,0.f,0.f,0.f};
#pragma unroll
      for (int kk = 0; kk < 4; ++kk) {
        int row = mt * 16 + l15;
        int off = (kk * 64 + l16 * 16) ^ ((row & 7) << 4);
        bf16x8 a = *(const bf16x8*)((const char*)sE + row * 256 + off);
        acc = __builtin_amdgcn_mfma_f32_16x16x32_bf16(a, wf[kk], acc, 0, 0, 0);
      }
      char* base = (char*)sT + (mt * 16 + l16 * 4) * 256;
#pragma unroll
      for (int r = 0; r < 4; ++r) {
        char* p = base + r * 256 + (cp ^ ((rb + r) << 4));
        float g = bf2f(*(unsigned short*)p);
        *(unsigned short*)p = f2bf(gelu_f(acc[r] + g));
      }
    }
  }
  __syncthreads();

  // ---- layer 2: sT x W2 + mb2 -> gelu -> sE
  {
    bf16x8 wf[4];
#pragma unroll
    for (int kk = 0; kk < 4; ++kk)
      wf[kk] = *(const bf16x8*)(WT2 + (size_t)colw * 128 + kk * 32 + l16 * 8);
    float bb = mb2[colw];
    for (int mt = 0; mt < 6; ++mt) {
      floatx4 acc = {0.f,0.f,0.f,0.f};
#pragma unroll
      for (int kk = 0; kk < 4; ++kk) {
        int row = mt * 16 + l15;
        int off = (kk * 64 + l16 * 16) ^ ((row & 7) << 4);
        bf16x8 a = *(const bf16x8*)((const char*)sT + row * 256 + off);
        acc = __builtin_amdgcn_mfma_f32_16x16x32_bf16(a, wf[kk], acc, 0, 0, 0);
      }
      char* base = (char*)sE + (mt * 16 + l16 * 4) * 256;
#pragma unroll
      for (int r = 0; r < 4; ++r) {
        char* p = base + r * 256 + (cp ^ ((rb + r) << 4));
        *(unsigned short*)p = f2bf(gelu_f(acc[r] + bb));
      }
    }
  }
  __syncthreads();

  // ---- layer 3: sE x W3, aggregate rows per node
  {
    bf16x8 wf[4];
#pragma unroll
    for (int kk = 0; kk < 4; ++kk)
      wf[kk] = *(const bf16x8*)(WT3 + (size_t)colw * 128 + kk * 32 + l16 * 8);
#pragma unroll
    for (int half = 0; half < 2; ++half) {
      float agga[4] = {0.f,0.f,0.f,0.f};
      for (int mt3 = 0; mt3 < 3; ++mt3) {
        int mt = half * 3 + mt3;
        floatx4 acc = {0.f,0.f,0.f,0.f};
#pragma unroll
        for (int kk = 0; kk < 4; ++kk) {
          int row = mt * 16 + l15;
          int off = (kk * 64 + l16 * 16) ^ ((row & 7) << 4);
          bf16x8 a = *(const bf16x8*)((const char*)sE + row * 256 + off);
          acc = __builtin_amdgcn_mfma_f32_16x16x32_bf16(a, wf[kk], acc, 0, 0, 0);
        }
#pragma unroll
        for (int r = 0; r < 4; ++r) agga[r] += acc[r];
      }
      float s = agga[0] + agga[1] + agga[2] + agga[3];
      s += __shfl_xor(s, 16);
      s += __shfl_xor(s, 32);
      if (lane < 16) {
        int col = w * 16 + lane;
        agg[(size_t)(i0 + half) * 128 + col] = s + 48.0f * mb3[col];
      }
    }
  }
}

// ---------------------------------------------------------------------------
// k3: node FF: h=LN(node_h+agg); ff=gelu(h@fW1+fb1)@fW2+fb2; out=LN(h+ff)
// ---------------------------------------------------------------------------
__global__ __launch_bounds__(256) void k3_ff(
    const float* node_h, const float* agg,
    const unsigned short* FWT1, const unsigned short* FWT2,
    const float* fb1, const float* fb2,
    const float* g1, const float* b1,
    const float* g2, const float* b2,
    float* out) {
  __shared__ __align__(16) unsigned short sH[32 * 128];
  __shared__ __align__(16) unsigned short sT3[32 * 512];
  __shared__ float sP[32 * 128];
  int r0 = blockIdx.x * 32;
  int tid = threadIdx.x, lane = tid & 63, w = tid >> 6;
  int l15 = lane & 15, l16 = lane >> 4;

  // load + LN1
  {
    int row = tid >> 3;
    int c0 = (tid & 7) * 16;
    const floatx4* nh4 = (const floatx4*)(node_h + (size_t)(r0 + row) * 128 + c0);
    const floatx4* ag4 = (const floatx4*)(agg + (size_t)(r0 + row) * 128 + c0);
    float x[16]; float sum = 0.f, sum2 = 0.f;
#pragma unroll
    for (int q4 = 0; q4 < 4; ++q4) {
      floatx4 a = nh4[q4], g = ag4[q4];
#pragma unroll
      for (int j = 0; j < 4; ++j) {
        float xv = a[j] + g[j];
        x[q4 * 4 + j] = xv; sum += xv; sum2 += xv * xv;
      }
    }
    sum  += __shfl_xor(sum, 1);  sum  += __shfl_xor(sum, 2);  sum  += __shfl_xor(sum, 4);
    sum2 += __shfl_xor(sum2, 1); sum2 += __shfl_xor(sum2, 2); sum2 += __shfl_xor(sum2, 4);
    float mu = sum * (1.f / 128.f);
    float var = sum2 * (1.f / 128.f) - mu * mu;
    float rstd = rsqrtf(var + 1e-5f);
#pragma unroll
    for (int q = 0; q < 16; ++q) {
      int col = c0 + q;
      float h = (x[q] - mu) * rstd * g1[col] + b1[col];
      sP[row * 128 + col] = h;
      char* p = (char*)sH + row * 256 + ((((col >> 3) ^ (row & 7)) << 4) | ((col & 7) << 1));
      *(unsigned short*)p = f2bf(h);
    }
  }
  __syncthreads();

  // GEMM1: sH @ FWT1 -> gelu -> sT3   [32,128]x[128,512]
  for (int nq = 0; nq < 8; ++nq) {
    int nt = w * 8 + nq;
    bf16x8 wf[4];
    for (int kk = 0; kk < 4; ++kk)
      wf[kk] = *(const bf16x8*)(FWT1 + (size_t)(nt * 16 + l15) * 128 + kk * 32 + l16 * 8);
    for (int mt = 0; mt < 2; ++mt) {
      floatx4 acc = {0.f,0.f,0.f,0.f};
      for (int kk = 0; kk < 4; ++kk) {
        int row = mt * 16 + l15;
        int off = (kk * 64 + l16 * 16) ^ ((row & 7) << 4);
        bf16x8 a = *(const bf16x8*)((const char*)sH + row * 256 + off);
        acc = __builtin_amdgcn_mfma_f32_16x16x32_bf16(a, wf[kk], acc, 0, 0, 0);
      }
      int col = nt * 16 + l15;
      float bb = fb1[col];
      for (int r = 0; r < 4; ++r) {
        int row = mt * 16 + l16 * 4 + r;
        char* p = (char*)sT3 + row * 1024 + ((((col >> 3) ^ (row & 7)) << 4) | ((col & 7) << 1));
        *(unsigned short*)p = f2bf(gelu_f(acc[r] + bb));
      }
    }
  }
  __syncthreads();

  // GEMM2: sT3 @ FWT2 + fb2 + h -> sP   [32,512]x[512,128]
  for (int n = 0; n < 2; ++n) {
    int nt = 2 * w + n;
    for (int mt = 0; mt < 2; ++mt) {
      floatx4 acc = {0.f,0.f,0.f,0.f};
      for (int kk = 0; kk < 16; ++kk) {
        int row = mt * 16 + l15;
        int off = (kk * 64 + l16 * 16) ^ ((row & 7) << 4);
        bf16x8 a = *(const bf16x8*)((const char*)sT3 + row * 1024 + off);
        bf16x8 b = *(const bf16x8*)(FWT2 + (size_t)(nt * 16 + l15) * 512 + kk * 32 + l16 * 8);
        acc = __builtin_amdgcn_mfma_f32_16x16x32_bf16(a, b, acc, 0, 0, 0);
      }
      int col = nt * 16 + l15;
      float bb = fb2[col];
      for (int r = 0; r < 4; ++r) {
        int row = mt * 16 + l16 * 4 + r;
        sP[row * 128 + col] += acc[r] + bb;
      }
    }
  }
  __syncthreads();

  // LN2 + store (fp32)
  {
    int row = tid >> 3;
    int c0 = (tid & 7) * 16;
    float x[16]; float sum = 0.f, sum2 = 0.f;
#pragma unroll
    for (int q = 0; q < 16; ++q) {
      float xv = sP[row * 128 + c0 + q];
      x[q] = xv; sum += xv; sum2 += xv * xv;
    }
    sum  += __shfl_xor(sum, 1);  sum  += __shfl_xor(sum, 2);  sum  += __shfl_xor(sum, 4);
    sum2 += __shfl_xor(sum2, 1); sum2 += __shfl_xor(sum2, 2); sum2 += __shfl_xor(sum2, 4);
    float mu = sum * (1.f / 128.f);
    float var = sum2 * (1.f / 128.f) - mu * mu;
    float rstd = rsqrtf(var + 1e-5f);
#pragma unroll
    for (int q = 0; q < 16; ++q) {
      int col = c0 + q;
      out[(size_t)(r0 + row) * 128 + col] = (x[q] - mu) * rstd * g2[col] + b2[col];
    }
  }
}

// ---------------------------------------------------------------------------
extern "C" void kernel_launch(void* const* d_in, const int* in_sizes, int n_in,
                              void* d_out, int out_size, void* d_ws, size_t ws_size,
                              hipStream_t stream) {
  const float* node_h  = (const float*)d_in[0];
  const float* edge_h  = (const float*)d_in[1];
  const int*   edge_idx= (const int*)d_in[2];
  const float* seq_emb = (const float*)d_in[3];
  const float* ar_mask = (const float*)d_in[4];
  const float* mW1 = (const float*)d_in[5];
  const float* mb1 = (const float*)d_in[6];
  const float* mW2 = (const float*)d_in[7];
  const float* mb2 = (const float*)d_in[8];
  const float* mW3 = (const float*)d_in[9];
  const float* mb3 = (const float*)d_in[10];
  const float* fW1 = (const float*)d_in[11];
  const float* fb1 = (const float*)d_in[12];
  const float* fW2 = (const float*)d_in[13];
  const float* fb2 = (const float*)d_in[14];
  const float* g1  = (const float*)d_in[15];
  const float* b1  = (const float*)d_in[16];
  const float* g2  = (const float*)d_in[17];
  const float* b2  = (const float*)d_in[18];

  char* ws = (char*)d_ws;
  unsigned short* MT1  = (unsigned short*)(ws + 0);        // [128][512] bf16
  unsigned short* WT2  = (unsigned short*)(ws + 131072);   // [128][128] bf16
  unsigned short* WT3  = (unsigned short*)(ws + 163840);   // [128][128] bf16
  unsigned short* FWT1 = (unsigned short*)(ws + 196608);   // [512][128] bf16
  unsigned short* FWT2 = (unsigned short*)(ws + 327680);   // [128][512] bf16
  float*          Apr  = (float*)(ws + 458752);            // [8192][128] f32
  unsigned short* BS   = (unsigned short*)(ws + 4653056);  // [8192][256] bf16
  float*          agg  = (float*)(ws + 8847360);           // [8192][128] f32

  hipLaunchKernelGGL(k0_transpose, dim3(224), dim3(256), 0, stream,
                     mW1, mW2, mW3, fW1, fW2, MT1, WT2, WT3, FWT1, FWT2);
  hipLaunchKernelGGL(k1_nodepre, dim3(256), dim3(256), 0, stream,
                     node_h, seq_emb, MT1, mb1, Apr, BS);
  hipLaunchKernelGGL(k2_edge, dim3(4096), dim3(512), 0, stream,
                     edge_h, edge_idx, ar_mask, MT1, WT2, WT3, mb2, mb3,
                     Apr, BS, agg);
  hipLaunchKernelGGL(k3_ff, dim3(256), dim3(256), 0, stream,
                     node_h, agg, FWT1, FWT2, fb1, fb2, g1, b1, g2, b2,
                     (float*)d_out);
}